// Round 4
// baseline (384.944 us; speedup 1.0000x reference)
//
#include <hip/hip_runtime.h>
#include <cstdint>
#include <cstddef>

// DecayAttention: B=2, T=2048, C=1024, H=16, DH=64
// out = proj( softmax( (QK^T * scale) * exp(-softplus(lambda_h)*|i-j|) ) V )

#define DEVI __device__ __forceinline__

typedef float f32x4 __attribute__((ext_vector_type(4)));
typedef short bf16x8 __attribute__((ext_vector_type(8)));

static constexpr int Bc = 2, Tc = 2048, Cc = 1024, Hc = 16, DHc = 64;

DEVI unsigned short f2bf(float f) {
  union { float f; unsigned u; } a; a.f = f;
  unsigned u = a.u;
  unsigned r = (u + 0x7fffu + ((u >> 16) & 1u)) >> 16;  // RNE
  return (unsigned short)r;
}

DEVI unsigned packbf(float lo, float hi) {
  return (unsigned)f2bf(lo) | ((unsigned)f2bf(hi) << 16);
}

DEVI void gload_lds16(const void* g, void* l) {
  __builtin_amdgcn_global_load_lds(
      (const __attribute__((address_space(1))) void*)g,
      (__attribute__((address_space(3))) void*)l, 16, 0, 0);
}

// ---------------------------------------------------------------- f32 -> bf16
__global__ __launch_bounds__(256) void k_cvt(const float* __restrict__ in,
                                             unsigned short* __restrict__ out,
                                             int n4) {
  int i = blockIdx.x * 256 + threadIdx.x;
  if (i >= n4) return;
  const float4 v = ((const float4*)in)[i];
  ushort4 o;
  o.x = f2bf(v.x); o.y = f2bf(v.y); o.z = f2bf(v.z); o.w = f2bf(v.w);
  ((ushort4*)out)[i] = o;
}

// ------------------------------------------------- NT GEMM: C = A * B^T + bias
// A [M][K] bf16 row-major, B [N][K] bf16 row-major, K % 32 == 0.
// 128x128 tile, 4 waves (2x2 quadrants of 64x64), 4x4 16x16x32 frags per wave.
template <int OUT_BF16>
__global__ __launch_bounds__(256) void k_gemm_nt(
    const unsigned short* __restrict__ A, const unsigned short* __restrict__ B,
    const float* __restrict__ bias, void* __restrict__ C, int K, int ldc) {
  __shared__ __align__(16) unsigned short As[128 * 32];
  __shared__ __align__(16) unsigned short Bs[128 * 32];
  const int tid = threadIdx.x, lane = tid & 63, wid = tid >> 6;
  const int wm = wid >> 1, wn = wid & 1;
  const int l15 = lane & 15, l4 = lane >> 4;
  f32x4 acc[4][4] = {};
  const int boff0 = wid * 2048 + lane * 16;  // staging byte offset (2 segs/wave)
  for (int k0 = 0; k0 < K; k0 += 32) {
    __syncthreads();
#pragma unroll
    for (int s = 0; s < 2; ++s) {
      const int boff = boff0 + s * 1024;
      const int row = boff >> 6, colb = boff & 63;  // 64 B per LDS row (32 bf16)
      gload_lds16((const char*)A + ((size_t)(blockIdx.y * 128 + row) * K + k0) * 2 + colb,
                  (char*)As + (wid * 2 + s) * 1024);
      gload_lds16((const char*)B + ((size_t)(blockIdx.x * 128 + row) * K + k0) * 2 + colb,
                  (char*)Bs + (wid * 2 + s) * 1024);
    }
    __syncthreads();
    bf16x8 af[4], bf[4];
#pragma unroll
    for (int i = 0; i < 4; ++i) {
      af[i] = *(const bf16x8*)(As + (wm * 64 + i * 16 + l15) * 32 + l4 * 8);
      bf[i] = *(const bf16x8*)(Bs + (wn * 64 + i * 16 + l15) * 32 + l4 * 8);
    }
#pragma unroll
    for (int mi = 0; mi < 4; ++mi)
#pragma unroll
      for (int ni = 0; ni < 4; ++ni)
        acc[mi][ni] = __builtin_amdgcn_mfma_f32_16x16x32_bf16(af[mi], bf[ni],
                                                              acc[mi][ni], 0, 0, 0);
  }
#pragma unroll
  for (int mi = 0; mi < 4; ++mi) {
    const int r0 = blockIdx.y * 128 + wm * 64 + mi * 16 + l4 * 4;
#pragma unroll
    for (int ni = 0; ni < 4; ++ni) {
      const int c = blockIdx.x * 128 + wn * 64 + ni * 16 + l15;
      const float bv = bias[c];
#pragma unroll
      for (int j = 0; j < 4; ++j) {
        const float v = acc[mi][ni][j] + bv;
        if (OUT_BF16)
          ((unsigned short*)C)[(size_t)(r0 + j) * ldc + c] = f2bf(v);
        else
          ((float*)C)[(size_t)(r0 + j) * ldc + c] = v;
      }
    }
  }
}

// ------------------------------------- V transpose: [B,T,H,DH] -> [B,H,DH,T]
__global__ __launch_bounds__(256) void k_vtrans(const unsigned short* __restrict__ qkv,
                                                unsigned short* __restrict__ vt) {
  __shared__ unsigned short tile[64][65];
  const int bh = blockIdx.y, b = bh >> 4, h = bh & 15;
  const int t0 = blockIdx.x * 64;
  const int tid = threadIdx.x;
#pragma unroll
  for (int r = 0; r < 16; ++r) {
    const int e = r * 256 + tid;
    const int row = e >> 6, col = e & 63;  // row = t offset, col = d
    tile[row][col] = qkv[(size_t)(b * Tc + t0 + row) * (3 * Cc) + 2 * Cc + h * DHc + col];
  }
  __syncthreads();
#pragma unroll
  for (int r = 0; r < 16; ++r) {
    const int e = r * 256 + tid;
    const int dd = e >> 6, tcol = e & 63;
    vt[((size_t)bh * DHc + dd) * Tc + t0 + tcol] = tile[tcol][dd];
  }
}

// --------------------------------------------------------- decay attention
// Swapped-operand flash attention, no max-subtraction (|s·decay| <~ 8).
// S^T = mfma(K, Q): lane holds col q = lane&15 (fixed), rows key = (lane>>4)*4+r.
// P^T -> B-frag via 8 shuffles; no per-tile reductions; l summed once at end.
// R4: XCD-local block mapping (all 32 q-blocks of one (b,h) on one XCD so K/V
// stay L2-resident) + ping-pong register prefetch of next K/V tile (latency
// hides under compute) + setprio around MFMA clusters.
__global__ __launch_bounds__(256, 4) void k_attn(const unsigned short* __restrict__ qkv,
                                                 const unsigned short* __restrict__ vt,
                                                 const float* __restrict__ lraw,
                                                 unsigned short* __restrict__ ao) {
  __shared__ float tbl[Tc];
  const int tid = threadIdx.x, lane = tid & 63, wid = tid >> 6;
  const int l15 = lane & 15, l4 = lane >> 4;
  // XCD-aware mapping: xcd = bid&7 (round-robin dispatch), 128 blocks per XCD
  // = 4 bh-groups x 32 q-blocks. K/V working set per XCD: 4 x 512KB = 2MB < L2.
  const int bid = blockIdx.x;
  const int xcd = bid & 7, j = bid >> 3;
  const int bh = xcd + 8 * (j >> 5);  // 0..31
  const int qtb = j & 31;
  const int b = bh >> 4, h = bh & 15;
  const int qt = qtb * 4 + wid;       // 0..127
  const float lam = log1pf(__expf(lraw[h]));  // softplus
  for (int i = tid; i < Tc; i += 256) tbl[i] = 0.125f * __expf(-lam * (float)i);
  __syncthreads();

  const int q = qt * 16 + l15;
  // Q as B-operand: col=q (l15), k = d = l4*8+j
  const unsigned short* qp = qkv + (size_t)(b * Tc + q) * (3 * Cc) + h * DHc + l4 * 8;
  const bf16x8 qf0 = *(const bf16x8*)qp;
  const bf16x8 qf1 = *(const bf16x8*)(qp + 32);

  // K as A-operand: row=key (l15 within 16-key tile), k = d
  const unsigned short* kbase =
      qkv + (size_t)(b * Tc + l15) * (3 * Cc) + Cc + h * DHc + l4 * 8;
  // V^T as A-operand: row=d (l15 within 16-d tile), k = key = l4*8+j
  const unsigned short* vbase = vt + (size_t)(bh * DHc + l15) * Tc + l4 * 8;
  constexpr size_t KSTEP = (size_t)32 * 3 * Cc;  // elements per 32-key tile

  const int src0 = l15 | ((l4 & 1) << 5);
  const bool hi = (l4 >= 2);
  f32x4 o[4] = {};
  float lsum = 0.f;

#define LOADK(KR, T)                                                        \
  do {                                                                      \
    const unsigned short* kp_ = kbase + (size_t)(T) * KSTEP;                \
    KR[0] = *(const bf16x8*)(kp_);                                          \
    KR[1] = *(const bf16x8*)(kp_ + 32);                                     \
    KR[2] = *(const bf16x8*)(kp_ + 16 * 3 * Cc);                            \
    KR[3] = *(const bf16x8*)(kp_ + 16 * 3 * Cc + 32);                       \
  } while (0)
#define LOADV(VR, T)                                                        \
  do {                                                                      \
    const unsigned short* vp_ = vbase + (T) * 32;                           \
    VR[0] = *(const bf16x8*)(vp_);                                          \
    VR[1] = *(const bf16x8*)(vp_ + 16 * Tc);                                \
    VR[2] = *(const bf16x8*)(vp_ + 32 * Tc);                                \
    VR[3] = *(const bf16x8*)(vp_ + 48 * Tc);                                \
  } while (0)

#define ATTN_STEP(KR, VR, KT)                                                    \
  do {                                                                           \
    f32x4 z0 = {}, z1 = {};                                                      \
    __builtin_amdgcn_s_setprio(1);                                               \
    z0 = __builtin_amdgcn_mfma_f32_16x16x32_bf16(KR[0], qf0, z0, 0, 0, 0);       \
    z0 = __builtin_amdgcn_mfma_f32_16x16x32_bf16(KR[1], qf1, z0, 0, 0, 0);       \
    z1 = __builtin_amdgcn_mfma_f32_16x16x32_bf16(KR[2], qf0, z1, 0, 0, 0);       \
    z1 = __builtin_amdgcn_mfma_f32_16x16x32_bf16(KR[3], qf1, z1, 0, 0, 0);       \
    __builtin_amdgcn_s_setprio(0);                                               \
    const int delta = q - (KT) * 32 - l4 * 4;                                    \
    float p0[4], p1[4];                                                          \
    _Pragma("unroll") for (int r = 0; r < 4; ++r) {                              \
      p0[r] = __expf(z0[r] * tbl[abs(delta - r)]);                               \
      p1[r] = __expf(z1[r] * tbl[abs(delta - 16 - r)]);                          \
      lsum += p0[r] + p1[r];                                                     \
    }                                                                            \
    const unsigned pk00 = packbf(p0[0], p0[1]);                                  \
    const unsigned pk01 = packbf(p0[2], p0[3]);                                  \
    const unsigned pk10 = packbf(p1[0], p1[1]);                                  \
    const unsigned pk11 = packbf(p1[2], p1[3]);                                  \
    const unsigned a0 = __shfl(pk00, src0, 64), b0 = __shfl(pk10, src0, 64);     \
    const unsigned a1 = __shfl(pk01, src0, 64), b1 = __shfl(pk11, src0, 64);     \
    const unsigned a2 = __shfl(pk00, src0 + 16, 64),                             \
                   b2 = __shfl(pk10, src0 + 16, 64);                             \
    const unsigned a3 = __shfl(pk01, src0 + 16, 64),                             \
                   b3 = __shfl(pk11, src0 + 16, 64);                             \
    union { unsigned u[4]; bf16x8 v; } pf;                                       \
    pf.u[0] = hi ? b0 : a0;                                                      \
    pf.u[1] = hi ? b1 : a1;                                                      \
    pf.u[2] = hi ? b2 : a2;                                                      \
    pf.u[3] = hi ? b3 : a3;                                                      \
    __builtin_amdgcn_s_setprio(1);                                               \
    o[0] = __builtin_amdgcn_mfma_f32_16x16x32_bf16(VR[0], pf.v, o[0], 0, 0, 0);  \
    o[1] = __builtin_amdgcn_mfma_f32_16x16x32_bf16(VR[1], pf.v, o[1], 0, 0, 0);  \
    o[2] = __builtin_amdgcn_mfma_f32_16x16x32_bf16(VR[2], pf.v, o[2], 0, 0, 0);  \
    o[3] = __builtin_amdgcn_mfma_f32_16x16x32_bf16(VR[3], pf.v, o[3], 0, 0, 0);  \
    __builtin_amdgcn_s_setprio(0);                                               \
  } while (0)

  // ping-pong register prefetch: load t+1 before computing t
  bf16x8 kA[4], vA[4], kB[4], vB[4];
  LOADK(kA, 0); LOADV(vA, 0);
  for (int kt = 0; kt < Tc / 32; kt += 2) {
    LOADK(kB, kt + 1); LOADV(vB, kt + 1);
    ATTN_STEP(kA, vA, kt);
    const int t2 = (kt + 2) & 63;  // wraps to 0 on last iter (harmless reload)
    LOADK(kA, t2); LOADV(vA, t2);
    ATTN_STEP(kB, vB, kt + 1);
  }
#undef LOADK
#undef LOADV
#undef ATTN_STEP

  // ---- final row-sum across the l4 groups (once, not per tile)
  lsum += __shfl_xor(lsum, 16, 64);
  lsum += __shfl_xor(lsum, 32, 64);
  const float rl = __builtin_amdgcn_rcpf(lsum);

  // ---- epilogue: lane holds O^T[d = di*16 + l4*4 + j][q = l15]
  unsigned short* aop = ao + (size_t)(b * Tc + q) * Cc + h * DHc + l4 * 4;
#pragma unroll
  for (int di = 0; di < 4; ++di)
#pragma unroll
    for (int j = 0; j < 4; ++j)
      aop[di * 16 + j] = f2bf(o[di][j] * rl);
}

// ---------------------------------------------------------------- launcher
extern "C" void kernel_launch(void* const* d_in, const int* in_sizes, int n_in,
                              void* d_out, int out_size, void* d_ws, size_t ws_size,
                              hipStream_t stream) {
  const float* x      = (const float*)d_in[0];  // [B,T,C]
  const float* qkv_w  = (const float*)d_in[1];  // [3C,C]
  const float* qkv_b  = (const float*)d_in[2];  // [3C]
  const float* proj_w = (const float*)d_in[3];  // [C,C]
  const float* proj_b = (const float*)d_in[4];  // [C]
  const float* lraw   = (const float*)d_in[5];  // [H]

  // workspace layout (bf16 as unsigned short)
  unsigned short* xb    = (unsigned short*)d_ws;       // 4096*1024   (reused as ao)
  unsigned short* wqkv  = xb + 4194304;                // 3072*1024
  unsigned short* wproj = wqkv + 3145728;              // 1024*1024
  unsigned short* qkvo  = wproj + 1048576;             // 4096*3072
  unsigned short* vt    = qkvo + 12582912;             // 32*64*2048
  unsigned short* ao    = xb;                          // reuse (x dead after GEMM1)

  k_cvt<<<4096, 256, 0, stream>>>(x, xb, 1048576);
  k_cvt<<<3072, 256, 0, stream>>>(qkv_w, wqkv, 786432);
  k_cvt<<<1024, 256, 0, stream>>>(proj_w, wproj, 262144);
  // qkv = x @ qkv_w^T + b  -> bf16 [4096][3072]
  k_gemm_nt<1><<<dim3(24, 32), 256, 0, stream>>>(xb, wqkv, qkv_b, qkvo, 1024, 3072);
  // V^T per head
  k_vtrans<<<dim3(32, 32), 256, 0, stream>>>(qkvo, vt);
  // decay attention -> bf16 [4096][1024]
  k_attn<<<1024, 256, 0, stream>>>(qkvo, vt, lraw, ao);
  // out = attn_out @ proj_w^T + b -> f32 d_out
  k_gemm_nt<0><<<dim3(8, 32), 256, 0, stream>>>(ao, wproj, proj_b, d_out, 1024, 1024);
}

// Round 6
// 237.850 us; speedup vs baseline: 1.6184x; 1.6184x over previous
//
#include <hip/hip_runtime.h>
#include <cstdint>
#include <cstddef>

// DecayAttention: B=2, T=2048, C=1024, H=16, DH=64
// out = proj( softmax( (QK^T * scale) * exp(-softplus(lambda_h)*|i-j|) ) V )

#define DEVI __device__ __forceinline__

typedef float f32x4 __attribute__((ext_vector_type(4)));
typedef short bf16x8 __attribute__((ext_vector_type(8)));

static constexpr int Bc = 2, Tc = 2048, Cc = 1024, Hc = 16, DHc = 64;

DEVI unsigned short f2bf(float f) {
  union { float f; unsigned u; } a; a.f = f;
  unsigned u = a.u;
  unsigned r = (u + 0x7fffu + ((u >> 16) & 1u)) >> 16;  // RNE
  return (unsigned short)r;
}

DEVI unsigned packbf(float lo, float hi) {
  return (unsigned)f2bf(lo) | ((unsigned)f2bf(hi) << 16);
}

DEVI void gload_lds16(const void* g, void* l) {
  __builtin_amdgcn_global_load_lds(
      (const __attribute__((address_space(1))) void*)g,
      (__attribute__((address_space(3))) void*)l, 16, 0, 0);
}

// ---------------------------------------------------------------- f32 -> bf16
__global__ __launch_bounds__(256) void k_cvt(const float* __restrict__ in,
                                             unsigned short* __restrict__ out,
                                             int n4) {
  int i = blockIdx.x * 256 + threadIdx.x;
  if (i >= n4) return;
  const float4 v = ((const float4*)in)[i];
  ushort4 o;
  o.x = f2bf(v.x); o.y = f2bf(v.y); o.z = f2bf(v.z); o.w = f2bf(v.w);
  ((ushort4*)out)[i] = o;
}

// ------------------------------------------------- NT GEMM: C = A * B^T + bias
template <int OUT_BF16>
__global__ __launch_bounds__(256) void k_gemm_nt(
    const unsigned short* __restrict__ A, const unsigned short* __restrict__ B,
    const float* __restrict__ bias, void* __restrict__ C, int K, int ldc) {
  __shared__ __align__(16) unsigned short As[128 * 32];
  __shared__ __align__(16) unsigned short Bs[128 * 32];
  const int tid = threadIdx.x, lane = tid & 63, wid = tid >> 6;
  const int wm = wid >> 1, wn = wid & 1;
  const int l15 = lane & 15, l4 = lane >> 4;
  f32x4 acc[4][4] = {};
  const int boff0 = wid * 2048 + lane * 16;  // staging byte offset (2 segs/wave)
  for (int k0 = 0; k0 < K; k0 += 32) {
    __syncthreads();
#pragma unroll
    for (int s = 0; s < 2; ++s) {
      const int boff = boff0 + s * 1024;
      const int row = boff >> 6, colb = boff & 63;  // 64 B per LDS row (32 bf16)
      gload_lds16((const char*)A + ((size_t)(blockIdx.y * 128 + row) * K + k0) * 2 + colb,
                  (char*)As + (wid * 2 + s) * 1024);
      gload_lds16((const char*)B + ((size_t)(blockIdx.x * 128 + row) * K + k0) * 2 + colb,
                  (char*)Bs + (wid * 2 + s) * 1024);
    }
    __syncthreads();
    bf16x8 af[4], bf[4];
#pragma unroll
    for (int i = 0; i < 4; ++i) {
      af[i] = *(const bf16x8*)(As + (wm * 64 + i * 16 + l15) * 32 + l4 * 8);
      bf[i] = *(const bf16x8*)(Bs + (wn * 64 + i * 16 + l15) * 32 + l4 * 8);
    }
#pragma unroll
    for (int mi = 0; mi < 4; ++mi)
#pragma unroll
      for (int ni = 0; ni < 4; ++ni)
        acc[mi][ni] = __builtin_amdgcn_mfma_f32_16x16x32_bf16(af[mi], bf[ni],
                                                              acc[mi][ni], 0, 0, 0);
  }
#pragma unroll
  for (int mi = 0; mi < 4; ++mi) {
    const int r0 = blockIdx.y * 128 + wm * 64 + mi * 16 + l4 * 4;
#pragma unroll
    for (int ni = 0; ni < 4; ++ni) {
      const int c = blockIdx.x * 128 + wn * 64 + ni * 16 + l15;
      const float bv = bias[c];
#pragma unroll
      for (int j = 0; j < 4; ++j) {
        const float v = acc[mi][ni][j] + bv;
        if (OUT_BF16)
          ((unsigned short*)C)[(size_t)(r0 + j) * ldc + c] = f2bf(v);
        else
          ((float*)C)[(size_t)(r0 + j) * ldc + c] = v;
      }
    }
  }
}

// ------------------------------------- V transpose: [B,T,H,DH] -> [B,H,DH,T]
__global__ __launch_bounds__(256) void k_vtrans(const unsigned short* __restrict__ qkv,
                                                unsigned short* __restrict__ vt) {
  __shared__ unsigned short tile[64][65];
  const int bh = blockIdx.y, b = bh >> 4, h = bh & 15;
  const int t0 = blockIdx.x * 64;
  const int tid = threadIdx.x;
#pragma unroll
  for (int r = 0; r < 16; ++r) {
    const int e = r * 256 + tid;
    const int row = e >> 6, col = e & 63;  // row = t offset, col = d
    tile[row][col] = qkv[(size_t)(b * Tc + t0 + row) * (3 * Cc) + 2 * Cc + h * DHc + col];
  }
  __syncthreads();
#pragma unroll
  for (int r = 0; r < 16; ++r) {
    const int e = r * 256 + tid;
    const int dd = e >> 6, tcol = e & 63;
    vt[((size_t)bh * DHc + dd) * Tc + t0 + tcol] = tile[tcol][dd];
  }
}

// --------------------------------------------------------- decay attention
// R5: LDS-staged K/V (shared across waves — R4 was L1/vecmem-bound on 16x
// redundant wave loads), 2 q-tiles per wave, double-buffered 64-key tiles,
// XOR-swizzled LDS layout via pre-swizzled global source (gload_lds dest
// must stay linear). Decay computed inline (2 chained exp), no table.
// Swapped-operand S^T = mfma(K,Q); P^T -> B-frag via 8 shuffles/q-tile;
// no max-subtraction (|s*decay| < ~8; far-field p == 1.0 exactly, as ref).
__global__ __launch_bounds__(256, 2) void k_attn(const unsigned short* __restrict__ qkv,
                                                 const unsigned short* __restrict__ vt,
                                                 const float* __restrict__ lraw,
                                                 unsigned short* __restrict__ ao) {
  __shared__ __align__(16) unsigned short Ks[2][4096];  // [64 keys][64 d] swz
  __shared__ __align__(16) unsigned short Vs[2][4096];  // [64 d][64 keys] swz
  const int tid = threadIdx.x, lane = tid & 63, wid = tid >> 6;
  const int l15 = lane & 15, l4 = lane >> 4;
  // XCD mapping: 512 blocks; per XCD: 4 bh-groups x 16 q-blocks (128 rows each)
  const int bid = blockIdx.x;
  const int xcd = bid & 7, jj = bid >> 3;
  const int bh = xcd + 8 * (jj >> 4);   // 0..31
  const int qblk = jj & 15;             // 0..15
  const int b = bh >> 4, h = bh & 15;
  const float lam = log1pf(__expf(lraw[h]));  // softplus
  const int qt0 = qblk * 8 + wid * 2;   // wave's q-tiles: qt0, qt0+1
  const int qA = qt0 * 16 + l15, qB = qA + 16;

  // Q fragments (B-operand): col=q (l15), k=d=l4*8+j
  const unsigned short* qpA = qkv + (size_t)(b * Tc + qA) * (3 * Cc) + h * DHc + l4 * 8;
  const unsigned short* qpB = qkv + (size_t)(b * Tc + qB) * (3 * Cc) + h * DHc + l4 * 8;
  const bf16x8 qfA0 = *(const bf16x8*)qpA, qfA1 = *(const bf16x8*)(qpA + 32);
  const bf16x8 qfB0 = *(const bf16x8*)qpB, qfB1 = *(const bf16x8*)(qpB + 32);

  // ---- staging source pointers (per-lane, pre-swizzled global addresses)
  // LDS 16B-unit (row, w) holds global unit (row, w ^ (row&7)).
  const unsigned short* kSrc[2];
  const unsigned short* vSrc[2];
#pragma unroll
  for (int rr = 0; rr < 2; ++rr) {
    const int slot = (rr * 4 + wid) * 64 + lane;  // 0..511
    const int row = slot >> 3, wu = slot & 7;
    kSrc[rr] = qkv + (size_t)(b * Tc + row) * (3 * Cc) + Cc + h * DHc + 8 * (wu ^ (row & 7));
    vSrc[rr] = vt + (size_t)(bh * DHc + row) * Tc + 8 * (wu ^ (row & 7));
  }
  constexpr size_t KTS = (size_t)64 * 3 * Cc;  // K elems per 64-key tile
  // LDS read byte-offsets (loop-invariant, per-lane)
  int koffs[2][4], voffs[2][4];
#pragma unroll
  for (int hf = 0; hf < 2; ++hf) {
    const int r0 = hf * 32 + l15, r1 = r0 + 16;
    koffs[hf][0] = r0 * 128 + ((l4 ^ (r0 & 7)) * 16);
    koffs[hf][1] = r0 * 128 + (((4 + l4) ^ (r0 & 7)) * 16);
    koffs[hf][2] = r1 * 128 + ((l4 ^ (r1 & 7)) * 16);
    koffs[hf][3] = r1 * 128 + (((4 + l4) ^ (r1 & 7)) * 16);
#pragma unroll
    for (int db = 0; db < 4; ++db) {
      const int rv = db * 16 + l15;
      voffs[hf][db] = rv * 128 + (((hf * 4 + l4) ^ (rv & 7)) * 16);
    }
  }

  const int src0 = l15 | ((l4 & 1) << 5);
  const bool hi = (l4 >= 2);
  f32x4 oA[4] = {}, oB[4] = {};
  float lsumA = 0.f, lsumB = 0.f;

#define STAGE(bb, t)                                                          \
  do {                                                                        \
    _Pragma("unroll") for (int rr = 0; rr < 2; ++rr) {                        \
      gload_lds16(kSrc[rr] + (size_t)(t) * KTS, &Ks[bb][(rr * 4 + wid) * 512]); \
      gload_lds16(vSrc[rr] + (t) * 64, &Vs[bb][(rr * 4 + wid) * 512]);        \
    }                                                                         \
  } while (0)

#define QTILE_P(zz0, zz1, delta_, lsum_, pf_)                                 \
  do {                                                                        \
    float p0[4], p1[4];                                                       \
    _Pragma("unroll") for (int r = 0; r < 4; ++r) {                           \
      const float d0 = 0.125f * __expf(-lam * (float)abs((delta_) - r));      \
      const float d1 = 0.125f * __expf(-lam * (float)abs((delta_) - 16 - r)); \
      p0[r] = __expf(zz0[r] * d0);                                            \
      p1[r] = __expf(zz1[r] * d1);                                            \
      lsum_ += p0[r] + p1[r];                                                 \
    }                                                                         \
    const unsigned pk00 = packbf(p0[0], p0[1]);                               \
    const unsigned pk01 = packbf(p0[2], p0[3]);                               \
    const unsigned pk10 = packbf(p1[0], p1[1]);                               \
    const unsigned pk11 = packbf(p1[2], p1[3]);                               \
    const unsigned a0 = __shfl(pk00, src0, 64), b0 = __shfl(pk10, src0, 64);  \
    const unsigned a1 = __shfl(pk01, src0, 64), b1 = __shfl(pk11, src0, 64);  \
    const unsigned a2 = __shfl(pk00, src0 + 16, 64),                          \
                   b2 = __shfl(pk10, src0 + 16, 64);                          \
    const unsigned a3 = __shfl(pk01, src0 + 16, 64),                          \
                   b3 = __shfl(pk11, src0 + 16, 64);                          \
    pf_.u[0] = hi ? b0 : a0;                                                  \
    pf_.u[1] = hi ? b1 : a1;                                                  \
    pf_.u[2] = hi ? b2 : a2;                                                  \
    pf_.u[3] = hi ? b3 : a3;                                                  \
  } while (0)

#define COMPUTE(bb, kb0)                                                          \
  do {                                                                            \
    const char* kL = (const char*)&Ks[bb][0];                                     \
    const char* vL = (const char*)&Vs[bb][0];                                     \
    _Pragma("unroll") for (int hf = 0; hf < 2; ++hf) {                            \
      const bf16x8 kg0 = *(const bf16x8*)(kL + koffs[hf][0]);                     \
      const bf16x8 kg1 = *(const bf16x8*)(kL + koffs[hf][1]);                     \
      const bf16x8 kg2 = *(const bf16x8*)(kL + koffs[hf][2]);                     \
      const bf16x8 kg3 = *(const bf16x8*)(kL + koffs[hf][3]);                     \
      f32x4 zA0 = {}, zA1 = {}, zB0 = {}, zB1 = {};                               \
      __builtin_amdgcn_s_setprio(1);                                              \
      zA0 = __builtin_amdgcn_mfma_f32_16x16x32_bf16(kg0, qfA0, zA0, 0, 0, 0);     \
      zA0 = __builtin_amdgcn_mfma_f32_16x16x32_bf16(kg1, qfA1, zA0, 0, 0, 0);     \
      zA1 = __builtin_amdgcn_mfma_f32_16x16x32_bf16(kg2, qfA0, zA1, 0, 0, 0);     \
      zA1 = __builtin_amdgcn_mfma_f32_16x16x32_bf16(kg3, qfA1, zA1, 0, 0, 0);     \
      zB0 = __builtin_amdgcn_mfma_f32_16x16x32_bf16(kg0, qfB0, zB0, 0, 0, 0);     \
      zB0 = __builtin_amdgcn_mfma_f32_16x16x32_bf16(kg1, qfB1, zB0, 0, 0, 0);     \
      zB1 = __builtin_amdgcn_mfma_f32_16x16x32_bf16(kg2, qfB0, zB1, 0, 0, 0);     \
      zB1 = __builtin_amdgcn_mfma_f32_16x16x32_bf16(kg3, qfB1, zB1, 0, 0, 0);     \
      __builtin_amdgcn_s_setprio(0);                                              \
      const int dA = qA - (kb0) - hf * 32 - l4 * 4;                               \
      const int dB = dA + 16;                                                     \
      union { unsigned u[4]; bf16x8 v; } pfA, pfB;                                \
      QTILE_P(zA0, zA1, dA, lsumA, pfA);                                          \
      QTILE_P(zB0, zB1, dB, lsumB, pfB);                                          \
      const bf16x8 v0 = *(const bf16x8*)(vL + voffs[hf][0]);                      \
      const bf16x8 v1 = *(const bf16x8*)(vL + voffs[hf][1]);                      \
      const bf16x8 v2 = *(const bf16x8*)(vL + voffs[hf][2]);                      \
      const bf16x8 v3 = *(const bf16x8*)(vL + voffs[hf][3]);                      \
      __builtin_amdgcn_s_setprio(1);                                              \
      oA[0] = __builtin_amdgcn_mfma_f32_16x16x32_bf16(v0, pfA.v, oA[0], 0, 0, 0); \
      oA[1] = __builtin_amdgcn_mfma_f32_16x16x32_bf16(v1, pfA.v, oA[1], 0, 0, 0); \
      oA[2] = __builtin_amdgcn_mfma_f32_16x16x32_bf16(v2, pfA.v, oA[2], 0, 0, 0); \
      oA[3] = __builtin_amdgcn_mfma_f32_16x16x32_bf16(v3, pfA.v, oA[3], 0, 0, 0); \
      oB[0] = __builtin_amdgcn_mfma_f32_16x16x32_bf16(v0, pfB.v, oB[0], 0, 0, 0); \
      oB[1] = __builtin_amdgcn_mfma_f32_16x16x32_bf16(v1, pfB.v, oB[1], 0, 0, 0); \
      oB[2] = __builtin_amdgcn_mfma_f32_16x16x32_bf16(v2, pfB.v, oB[2], 0, 0, 0); \
      oB[3] = __builtin_amdgcn_mfma_f32_16x16x32_bf16(v3, pfB.v, oB[3], 0, 0, 0); \
      __builtin_amdgcn_s_setprio(0);                                              \
    }                                                                             \
  } while (0)

  STAGE(0, 0);
  __syncthreads();
  for (int t = 0; t < 32; t += 2) {
    STAGE(1, t + 1);
    COMPUTE(0, t * 64);
    __syncthreads();  // drains vmcnt (stage into buf1) + lgkm
    STAGE(0, (t + 2) & 31);
    COMPUTE(1, (t + 1) * 64);
    __syncthreads();
  }
#undef STAGE
#undef QTILE_P
#undef COMPUTE

  // ---- final row-sums (once)
  lsumA += __shfl_xor(lsumA, 16, 64);
  lsumA += __shfl_xor(lsumA, 32, 64);
  lsumB += __shfl_xor(lsumB, 16, 64);
  lsumB += __shfl_xor(lsumB, 32, 64);
  const float rlA = __builtin_amdgcn_rcpf(lsumA);
  const float rlB = __builtin_amdgcn_rcpf(lsumB);

  // ---- epilogue: lane holds O^T[d = di*16 + l4*4 + j][q = l15]
  unsigned short* aopA = ao + (size_t)(b * Tc + qA) * Cc + h * DHc + l4 * 4;
  unsigned short* aopB = ao + (size_t)(b * Tc + qB) * Cc + h * DHc + l4 * 4;
#pragma unroll
  for (int di = 0; di < 4; ++di)
#pragma unroll
    for (int j = 0; j < 4; ++j) {
      aopA[di * 16 + j] = f2bf(oA[di][j] * rlA);
      aopB[di * 16 + j] = f2bf(oB[di][j] * rlB);
    }
}

// ---------------------------------------------------------------- launcher
extern "C" void kernel_launch(void* const* d_in, const int* in_sizes, int n_in,
                              void* d_out, int out_size, void* d_ws, size_t ws_size,
                              hipStream_t stream) {
  const float* x      = (const float*)d_in[0];  // [B,T,C]
  const float* qkv_w  = (const float*)d_in[1];  // [3C,C]
  const float* qkv_b  = (const float*)d_in[2];  // [3C]
  const float* proj_w = (const float*)d_in[3];  // [C,C]
  const float* proj_b = (const float*)d_in[4];  // [C]
  const float* lraw   = (const float*)d_in[5];  // [H]

  // workspace layout (bf16 as unsigned short)
  unsigned short* xb    = (unsigned short*)d_ws;       // 4096*1024   (reused as ao)
  unsigned short* wqkv  = xb + 4194304;                // 3072*1024
  unsigned short* wproj = wqkv + 3145728;              // 1024*1024
  unsigned short* qkvo  = wproj + 1048576;             // 4096*3072
  unsigned short* vt    = qkvo + 12582912;             // 32*64*2048
  unsigned short* ao    = xb;                          // reuse (x dead after GEMM1)

  k_cvt<<<4096, 256, 0, stream>>>(x, xb, 1048576);
  k_cvt<<<3072, 256, 0, stream>>>(qkv_w, wqkv, 786432);
  k_cvt<<<1024, 256, 0, stream>>>(proj_w, wproj, 262144);
  // qkv = x @ qkv_w^T + b  -> bf16 [4096][3072]
  k_gemm_nt<1><<<dim3(24, 32), 256, 0, stream>>>(xb, wqkv, qkv_b, qkvo, 1024, 3072);
  // V^T per head
  k_vtrans<<<dim3(32, 32), 256, 0, stream>>>(qkvo, vt);
  // decay attention -> bf16 [4096][1024]
  k_attn<<<512, 256, 0, stream>>>(qkvo, vt, lraw, ao);
  // out = attn_out @ proj_w^T + b -> f32 d_out
  k_gemm_nt<0><<<dim3(8, 32), 256, 0, stream>>>(ao, wproj, proj_b, d_out, 1024, 1024);
}

// Round 7
// 187.308 us; speedup vs baseline: 2.0551x; 1.2698x over previous
//
#include <hip/hip_runtime.h>
#include <cstdint>
#include <cstddef>

// DecayAttention: B=2, T=2048, C=1024, H=16, DH=64
// out = proj( softmax( (QK^T * scale) * exp(-softplus(lambda_h)*|i-j|) ) V )

#define DEVI __device__ __forceinline__

typedef float f32x4 __attribute__((ext_vector_type(4)));
typedef short bf16x8 __attribute__((ext_vector_type(8)));

static constexpr int Bc = 2, Tc = 2048, Cc = 1024, Hc = 16, DHc = 64;

DEVI unsigned short f2bf(float f) {
  union { float f; unsigned u; } a; a.f = f;
  unsigned u = a.u;
  unsigned r = (u + 0x7fffu + ((u >> 16) & 1u)) >> 16;  // RNE
  return (unsigned short)r;
}

DEVI float bf2f(unsigned short u) {
  union { unsigned u; float f; } a; a.u = ((unsigned)u) << 16;
  return a.f;
}

DEVI unsigned packbf(float lo, float hi) {
  return (unsigned)f2bf(lo) | ((unsigned)f2bf(hi) << 16);
}

DEVI void gload_lds16(const void* g, void* l) {
  __builtin_amdgcn_global_load_lds(
      (const __attribute__((address_space(1))) void*)g,
      (__attribute__((address_space(3))) void*)l, 16, 0, 0);
}

// ---------------------------------------------------------------- f32 -> bf16
__global__ __launch_bounds__(256) void k_cvt(const float* __restrict__ in,
                                             unsigned short* __restrict__ out,
                                             int n4) {
  int i = blockIdx.x * 256 + threadIdx.x;
  if (i >= n4) return;
  const float4 v = ((const float4*)in)[i];
  ushort4 o;
  o.x = f2bf(v.x); o.y = f2bf(v.y); o.z = f2bf(v.z); o.w = f2bf(v.w);
  ((ushort4*)out)[i] = o;
}

// ------------------------------------------------- NT GEMM: C = A * B^T + bias
template <int OUT_BF16>
__global__ __launch_bounds__(256) void k_gemm_nt(
    const unsigned short* __restrict__ A, const unsigned short* __restrict__ B,
    const float* __restrict__ bias, void* __restrict__ C, int K, int ldc) {
  __shared__ __align__(16) unsigned short As[128 * 32];
  __shared__ __align__(16) unsigned short Bs[128 * 32];
  const int tid = threadIdx.x, lane = tid & 63, wid = tid >> 6;
  const int wm = wid >> 1, wn = wid & 1;
  const int l15 = lane & 15, l4 = lane >> 4;
  f32x4 acc[4][4] = {};
  const int boff0 = wid * 2048 + lane * 16;  // staging byte offset (2 segs/wave)
  for (int k0 = 0; k0 < K; k0 += 32) {
    __syncthreads();
#pragma unroll
    for (int s = 0; s < 2; ++s) {
      const int boff = boff0 + s * 1024;
      const int row = boff >> 6, colb = boff & 63;  // 64 B per LDS row (32 bf16)
      gload_lds16((const char*)A + ((size_t)(blockIdx.y * 128 + row) * K + k0) * 2 + colb,
                  (char*)As + (wid * 2 + s) * 1024);
      gload_lds16((const char*)B + ((size_t)(blockIdx.x * 128 + row) * K + k0) * 2 + colb,
                  (char*)Bs + (wid * 2 + s) * 1024);
    }
    __syncthreads();
    bf16x8 af[4], bf[4];
#pragma unroll
    for (int i = 0; i < 4; ++i) {
      af[i] = *(const bf16x8*)(As + (wm * 64 + i * 16 + l15) * 32 + l4 * 8);
      bf[i] = *(const bf16x8*)(Bs + (wn * 64 + i * 16 + l15) * 32 + l4 * 8);
    }
#pragma unroll
    for (int mi = 0; mi < 4; ++mi)
#pragma unroll
      for (int ni = 0; ni < 4; ++ni)
        acc[mi][ni] = __builtin_amdgcn_mfma_f32_16x16x32_bf16(af[mi], bf[ni],
                                                              acc[mi][ni], 0, 0, 0);
  }
#pragma unroll
  for (int mi = 0; mi < 4; ++mi) {
    const int r0 = blockIdx.y * 128 + wm * 64 + mi * 16 + l4 * 4;
#pragma unroll
    for (int ni = 0; ni < 4; ++ni) {
      const int c = blockIdx.x * 128 + wn * 64 + ni * 16 + l15;
      const float bv = bias[c];
#pragma unroll
      for (int j = 0; j < 4; ++j) {
        const float v = acc[mi][ni][j] + bv;
        if (OUT_BF16)
          ((unsigned short*)C)[(size_t)(r0 + j) * ldc + c] = f2bf(v);
        else
          ((float*)C)[(size_t)(r0 + j) * ldc + c] = v;
      }
    }
  }
}

// --------- V transpose: [B,T,H,DH] -> [B,H,DH,T], plus per-64-key-tile V sums
__global__ __launch_bounds__(256) void k_vtrans(const unsigned short* __restrict__ qkv,
                                                unsigned short* __restrict__ vt,
                                                float* __restrict__ vsum) {
  __shared__ unsigned short tile[64][65];
  __shared__ float psum[4][64];
  const int bh = blockIdx.y, b = bh >> 4, h = bh & 15;
  const int t0 = blockIdx.x * 64;
  const int tid = threadIdx.x;
#pragma unroll
  for (int r = 0; r < 16; ++r) {
    const int e = r * 256 + tid;
    const int row = e >> 6, col = e & 63;  // row = t offset, col = d
    tile[row][col] = qkv[(size_t)(b * Tc + t0 + row) * (3 * Cc) + 2 * Cc + h * DHc + col];
  }
  __syncthreads();
#pragma unroll
  for (int r = 0; r < 16; ++r) {
    const int e = r * 256 + tid;
    const int dd = e >> 6, tcol = e & 63;
    vt[((size_t)bh * DHc + dd) * Tc + t0 + tcol] = tile[tcol][dd];
  }
  // per-tile V column sums (for far-field prefix)
  const int d = tid & 63, part = tid >> 6;
  float s = 0.f;
#pragma unroll
  for (int k = 0; k < 16; ++k) s += bf2f(tile[part * 16 + k][d]);
  psum[part][d] = s;
  __syncthreads();
  if (tid < 64)
    vsum[((size_t)bh * 32 + blockIdx.x) * 64 + tid] =
        psum[0][tid] + psum[1][tid] + psum[2][tid] + psum[3][tid];
}

// --------------- prefix over key tiles: vpre[bh][t][d] = sum_{k<64t} V[k][d]
__global__ __launch_bounds__(64) void k_prefix(const float* __restrict__ vsum,
                                               float* __restrict__ vpre) {
  const int bh = blockIdx.x, d = threadIdx.x;
  float run = 0.f;
  for (int t = 0; t < 32; ++t) {
    vpre[((size_t)bh * 33 + t) * 64 + d] = run;
    run += vsum[((size_t)bh * 32 + t) * 64 + d];
  }
  vpre[((size_t)bh * 33 + 32) * 64 + d] = run;
}

// --------------------------------------------------------- decay attention
// R7: far-field cutoff. For dist > D* = ceil(18.5/lam), z*decay < ~1e-7 so
// p = exp(z*decay) == 1.0f exactly (same in the f32 reference). Those keys'
// contribution is sum(V) with weight 1 -> seeded from f32 prefix sums; the
// key loop runs only over the ~10 near tiles. In-loop math unchanged (R6):
// LDS-staged K/V shared across waves, XOR-swizzle via pre-swizzled global
// source, swapped-operand S^T = mfma(K,Q), P^T->B-frag via 8 shuffles,
// no max-subtraction (|z*decay| < ~8).
__global__ __launch_bounds__(256, 2) void k_attn(const unsigned short* __restrict__ qkv,
                                                 const unsigned short* __restrict__ vt,
                                                 const float* __restrict__ lraw,
                                                 const float* __restrict__ vpre,
                                                 unsigned short* __restrict__ ao) {
  __shared__ __align__(16) unsigned short Ks[2][4096];  // [64 keys][64 d] swz
  __shared__ __align__(16) unsigned short Vs[2][4096];  // [64 d][64 keys] swz
  const int tid = threadIdx.x, lane = tid & 63, wid = tid >> 6;
  const int l15 = lane & 15, l4 = lane >> 4;
  // XCD mapping: 512 blocks; per XCD: 4 bh-groups x 16 q-blocks (128 rows each)
  const int bid = blockIdx.x;
  const int xcd = bid & 7, jj = bid >> 3;
  const int bh = xcd + 8 * (jj >> 4);   // 0..31
  const int qblk = jj & 15;             // 0..15
  const int b = bh >> 4, h = bh & 15;
  const float lam = log1pf(__expf(lraw[h]));  // softplus
  const int qt0 = qblk * 8 + wid * 2;   // wave's q-tiles: qt0, qt0+1
  const int qA = qt0 * 16 + l15, qB = qA + 16;

  // ---- far-field band
  const int Dstar = (int)fminf(2048.0f, ceilf(18.5f / lam));
  const int q0 = qblk * 128;
  const int t_lo = (q0 > Dstar) ? ((q0 - Dstar) >> 6) : 0;
  const int t_end = min(32, (q0 + Dstar + 191) >> 6);  // first fully-far upper tile
  const int nfar = 64 * t_lo + (Tc - 64 * t_end);      // keys with p == 1 exactly

  // Q fragments (B-operand): col=q (l15), k=d=l4*8+j
  const unsigned short* qpA = qkv + (size_t)(b * Tc + qA) * (3 * Cc) + h * DHc + l4 * 8;
  const unsigned short* qpB = qkv + (size_t)(b * Tc + qB) * (3 * Cc) + h * DHc + l4 * 8;
  const bf16x8 qfA0 = *(const bf16x8*)qpA, qfA1 = *(const bf16x8*)(qpA + 32);
  const bf16x8 qfB0 = *(const bf16x8*)qpB, qfB1 = *(const bf16x8*)(qpB + 32);

  // ---- staging source pointers (per-lane, pre-swizzled global addresses)
  // LDS 16B-unit (row, w) holds global unit (row, w ^ (row&7)).
  const unsigned short* kSrc[2];
  const unsigned short* vSrc[2];
#pragma unroll
  for (int rr = 0; rr < 2; ++rr) {
    const int slot = (rr * 4 + wid) * 64 + lane;  // 0..511
    const int row = slot >> 3, wu = slot & 7;
    kSrc[rr] = qkv + (size_t)(b * Tc + row) * (3 * Cc) + Cc + h * DHc + 8 * (wu ^ (row & 7));
    vSrc[rr] = vt + (size_t)(bh * DHc + row) * Tc + 8 * (wu ^ (row & 7));
  }
  constexpr size_t KTS = (size_t)64 * 3 * Cc;  // K elems per 64-key tile
  // LDS read byte-offsets (loop-invariant, per-lane)
  int koffs[2][4], voffs[2][4];
#pragma unroll
  for (int hf = 0; hf < 2; ++hf) {
    const int r0 = hf * 32 + l15, r1 = r0 + 16;
    koffs[hf][0] = r0 * 128 + ((l4 ^ (r0 & 7)) * 16);
    koffs[hf][1] = r0 * 128 + (((4 + l4) ^ (r0 & 7)) * 16);
    koffs[hf][2] = r1 * 128 + ((l4 ^ (r1 & 7)) * 16);
    koffs[hf][3] = r1 * 128 + (((4 + l4) ^ (r1 & 7)) * 16);
#pragma unroll
    for (int db = 0; db < 4; ++db) {
      const int rv = db * 16 + l15;
      voffs[hf][db] = rv * 128 + (((hf * 4 + l4) ^ (rv & 7)) * 16);
    }
  }

  const int src0 = l15 | ((l4 & 1) << 5);
  const bool hi = (l4 >= 2);

  // ---- seed O with far-field V sums (weight exactly 1), lsum with far count
  f32x4 oA[4], oB[4];
  {
    const float* pre_lo = vpre + ((size_t)bh * 33 + t_lo) * 64;
    const float* pre_hi = vpre + ((size_t)bh * 33 + t_end) * 64;
    const float* pre_all = vpre + ((size_t)bh * 33 + 32) * 64;
#pragma unroll
    for (int di = 0; di < 4; ++di)
#pragma unroll
      for (int j = 0; j < 4; ++j) {
        const int d = di * 16 + l4 * 4 + j;
        const float far = pre_lo[d] + (pre_all[d] - pre_hi[d]);
        oA[di][j] = far;
        oB[di][j] = far;
      }
  }
  float lsumA = 0.f, lsumB = 0.f;

#define STAGE(bb, t)                                                          \
  do {                                                                        \
    _Pragma("unroll") for (int rr = 0; rr < 2; ++rr) {                        \
      gload_lds16(kSrc[rr] + (size_t)(t) * KTS, &Ks[bb][(rr * 4 + wid) * 512]); \
      gload_lds16(vSrc[rr] + (t) * 64, &Vs[bb][(rr * 4 + wid) * 512]);        \
    }                                                                         \
  } while (0)

#define QTILE_P(zz0, zz1, delta_, lsum_, pf_)                                 \
  do {                                                                        \
    float p0[4], p1[4];                                                       \
    _Pragma("unroll") for (int r = 0; r < 4; ++r) {                           \
      const float d0 = 0.125f * __expf(-lam * (float)abs((delta_) - r));      \
      const float d1 = 0.125f * __expf(-lam * (float)abs((delta_) - 16 - r)); \
      p0[r] = __expf(zz0[r] * d0);                                            \
      p1[r] = __expf(zz1[r] * d1);                                            \
      lsum_ += p0[r] + p1[r];                                                 \
    }                                                                         \
    const unsigned pk00 = packbf(p0[0], p0[1]);                               \
    const unsigned pk01 = packbf(p0[2], p0[3]);                               \
    const unsigned pk10 = packbf(p1[0], p1[1]);                               \
    const unsigned pk11 = packbf(p1[2], p1[3]);                               \
    const unsigned a0 = __shfl(pk00, src0, 64), b0 = __shfl(pk10, src0, 64);  \
    const unsigned a1 = __shfl(pk01, src0, 64), b1 = __shfl(pk11, src0, 64);  \
    const unsigned a2 = __shfl(pk00, src0 + 16, 64),                          \
                   b2 = __shfl(pk10, src0 + 16, 64);                          \
    const unsigned a3 = __shfl(pk01, src0 + 16, 64),                          \
                   b3 = __shfl(pk11, src0 + 16, 64);                          \
    pf_.u[0] = hi ? b0 : a0;                                                  \
    pf_.u[1] = hi ? b1 : a1;                                                  \
    pf_.u[2] = hi ? b2 : a2;                                                  \
    pf_.u[3] = hi ? b3 : a3;                                                  \
  } while (0)

#define COMPUTE(bb, kb0)                                                          \
  do {                                                                            \
    const char* kL = (const char*)&Ks[bb][0];                                     \
    const char* vL = (const char*)&Vs[bb][0];                                     \
    _Pragma("unroll") for (int hf = 0; hf < 2; ++hf) {                            \
      const bf16x8 kg0 = *(const bf16x8*)(kL + koffs[hf][0]);                     \
      const bf16x8 kg1 = *(const bf16x8*)(kL + koffs[hf][1]);                     \
      const bf16x8 kg2 = *(const bf16x8*)(kL + koffs[hf][2]);                     \
      const bf16x8 kg3 = *(const bf16x8*)(kL + koffs[hf][3]);                     \
      f32x4 zA0 = {}, zA1 = {}, zB0 = {}, zB1 = {};                               \
      __builtin_amdgcn_s_setprio(1);                                              \
      zA0 = __builtin_amdgcn_mfma_f32_16x16x32_bf16(kg0, qfA0, zA0, 0, 0, 0);     \
      zA0 = __builtin_amdgcn_mfma_f32_16x16x32_bf16(kg1, qfA1, zA0, 0, 0, 0);     \
      zA1 = __builtin_amdgcn_mfma_f32_16x16x32_bf16(kg2, qfA0, zA1, 0, 0, 0);     \
      zA1 = __builtin_amdgcn_mfma_f32_16x16x32_bf16(kg3, qfA1, zA1, 0, 0, 0);     \
      zB0 = __builtin_amdgcn_mfma_f32_16x16x32_bf16(kg0, qfB0, zB0, 0, 0, 0);     \
      zB0 = __builtin_amdgcn_mfma_f32_16x16x32_bf16(kg1, qfB1, zB0, 0, 0, 0);     \
      zB1 = __builtin_amdgcn_mfma_f32_16x16x32_bf16(kg2, qfB0, zB1, 0, 0, 0);     \
      zB1 = __builtin_amdgcn_mfma_f32_16x16x32_bf16(kg3, qfB1, zB1, 0, 0, 0);     \
      __builtin_amdgcn_s_setprio(0);                                              \
      const int dA = qA - (kb0) - hf * 32 - l4 * 4;                               \
      const int dB = dA + 16;                                                     \
      union { unsigned u[4]; bf16x8 v; } pfA, pfB;                                \
      QTILE_P(zA0, zA1, dA, lsumA, pfA);                                          \
      QTILE_P(zB0, zB1, dB, lsumB, pfB);                                          \
      const bf16x8 v0 = *(const bf16x8*)(vL + voffs[hf][0]);                      \
      const bf16x8 v1 = *(const bf16x8*)(vL + voffs[hf][1]);                      \
      const bf16x8 v2 = *(const bf16x8*)(vL + voffs[hf][2]);                      \
      const bf16x8 v3 = *(const bf16x8*)(vL + voffs[hf][3]);                      \
      __builtin_amdgcn_s_setprio(1);                                              \
      oA[0] = __builtin_amdgcn_mfma_f32_16x16x32_bf16(v0, pfA.v, oA[0], 0, 0, 0); \
      oA[1] = __builtin_amdgcn_mfma_f32_16x16x32_bf16(v1, pfA.v, oA[1], 0, 0, 0); \
      oA[2] = __builtin_amdgcn_mfma_f32_16x16x32_bf16(v2, pfA.v, oA[2], 0, 0, 0); \
      oA[3] = __builtin_amdgcn_mfma_f32_16x16x32_bf16(v3, pfA.v, oA[3], 0, 0, 0); \
      oB[0] = __builtin_amdgcn_mfma_f32_16x16x32_bf16(v0, pfB.v, oB[0], 0, 0, 0); \
      oB[1] = __builtin_amdgcn_mfma_f32_16x16x32_bf16(v1, pfB.v, oB[1], 0, 0, 0); \
      oB[2] = __builtin_amdgcn_mfma_f32_16x16x32_bf16(v2, pfB.v, oB[2], 0, 0, 0); \
      oB[3] = __builtin_amdgcn_mfma_f32_16x16x32_bf16(v3, pfB.v, oB[3], 0, 0, 0); \
      __builtin_amdgcn_s_setprio(0);                                              \
    }                                                                             \
  } while (0)

  STAGE(0, t_lo);
  __syncthreads();
  for (int t = t_lo; t < t_end; ++t) {
    const int bb = (t - t_lo) & 1;
    const int tn = (t + 1 < t_end) ? (t + 1) : t_lo;  // dummy restage on last
    STAGE(bb ^ 1, tn);
    COMPUTE(bb, t * 64);
    __syncthreads();  // staging into bb^1 done; bb free for next STAGE
  }
#undef STAGE
#undef QTILE_P
#undef COMPUTE

  // ---- final row-sums (once) + far count
  lsumA += __shfl_xor(lsumA, 16, 64);
  lsumA += __shfl_xor(lsumA, 32, 64);
  lsumB += __shfl_xor(lsumB, 16, 64);
  lsumB += __shfl_xor(lsumB, 32, 64);
  const float rlA = __builtin_amdgcn_rcpf(lsumA + (float)nfar);
  const float rlB = __builtin_amdgcn_rcpf(lsumB + (float)nfar);

  // ---- epilogue: lane holds O^T[d = di*16 + l4*4 + j][q = l15]
  unsigned short* aopA = ao + (size_t)(b * Tc + qA) * Cc + h * DHc + l4 * 4;
  unsigned short* aopB = ao + (size_t)(b * Tc + qB) * Cc + h * DHc + l4 * 4;
#pragma unroll
  for (int di = 0; di < 4; ++di)
#pragma unroll
    for (int j = 0; j < 4; ++j) {
      aopA[di * 16 + j] = f2bf(oA[di][j] * rlA);
      aopB[di * 16 + j] = f2bf(oB[di][j] * rlB);
    }
}

// ---------------------------------------------------------------- launcher
extern "C" void kernel_launch(void* const* d_in, const int* in_sizes, int n_in,
                              void* d_out, int out_size, void* d_ws, size_t ws_size,
                              hipStream_t stream) {
  const float* x      = (const float*)d_in[0];  // [B,T,C]
  const float* qkv_w  = (const float*)d_in[1];  // [3C,C]
  const float* qkv_b  = (const float*)d_in[2];  // [3C]
  const float* proj_w = (const float*)d_in[3];  // [C,C]
  const float* proj_b = (const float*)d_in[4];  // [C]
  const float* lraw   = (const float*)d_in[5];  // [H]

  // workspace layout (bf16 as unsigned short)
  unsigned short* xb    = (unsigned short*)d_ws;       // 4096*1024   (reused as ao)
  unsigned short* wqkv  = xb + 4194304;                // 3072*1024
  unsigned short* wproj = wqkv + 3145728;              // 1024*1024
  unsigned short* qkvo  = wproj + 1048576;             // 4096*3072
  unsigned short* vt    = qkvo + 12582912;             // 32*64*2048
  float*          vsum  = (float*)(vt + 4194304);      // 32*32*64 f32
  float*          vpre  = vsum + 65536;                // 32*33*64 f32
  unsigned short* ao    = xb;                          // reuse (x dead after GEMM1)

  k_cvt<<<4096, 256, 0, stream>>>(x, xb, 1048576);
  k_cvt<<<3072, 256, 0, stream>>>(qkv_w, wqkv, 786432);
  k_cvt<<<1024, 256, 0, stream>>>(proj_w, wproj, 262144);
  // qkv = x @ qkv_w^T + b  -> bf16 [4096][3072]
  k_gemm_nt<1><<<dim3(24, 32), 256, 0, stream>>>(xb, wqkv, qkv_b, qkvo, 1024, 3072);
  // V^T per head + per-tile V sums
  k_vtrans<<<dim3(32, 32), 256, 0, stream>>>(qkvo, vt, vsum);
  // prefix sums over key tiles
  k_prefix<<<32, 64, 0, stream>>>(vsum, vpre);
  // decay attention -> bf16 [4096][1024]
  k_attn<<<512, 256, 0, stream>>>(qkvo, vt, lraw, vpre, ao);
  // out = attn_out @ proj_w^T + b -> f32 d_out
  k_gemm_nt<0><<<dim3(8, 32), 256, 0, stream>>>(ao, wproj, proj_b, d_out, 1024, 1024);
}